// Round 1
// baseline (1519.476 us; speedup 1.0000x reference)
//
#include <hip/hip_runtime.h>
#include <hip/hip_bf16.h>
#include <math.h>

#define N_NODES 100000
#define N_EDGES 6400000
#define D_IN 512
#define D_HID 16

// ---------------- degree ----------------
__global__ void deg_kernel(const int* __restrict__ dst, int* __restrict__ deg) {
    int e = blockIdx.x * blockDim.x + threadIdx.x;
    if (e < N_EDGES) atomicAdd(&deg[dst[e]], 1);
}

__global__ void dinv_kernel(const int* __restrict__ deg, float* __restrict__ dinv) {
    int i = blockIdx.x * blockDim.x + threadIdx.x;
    if (i < N_NODES) dinv[i] = rsqrtf((float)deg[i] + 1.0f);  // +1 self-loop
}

// ---------------- prefix sum over deg (chunk=1024/block) ----------------
__global__ void scan1(const int* __restrict__ deg, int* __restrict__ row_start,
                      int* __restrict__ bsum) {
    __shared__ int sd[256];
    int tid = threadIdx.x;
    int base = blockIdx.x * 1024 + tid * 4;
    int d0 = 0, d1 = 0, d2 = 0, d3 = 0;
    if (base + 3 < N_NODES) {
        d0 = deg[base]; d1 = deg[base + 1]; d2 = deg[base + 2]; d3 = deg[base + 3];
    } else {
        if (base < N_NODES) d0 = deg[base];
        if (base + 1 < N_NODES) d1 = deg[base + 1];
        if (base + 2 < N_NODES) d2 = deg[base + 2];
    }
    int s = d0 + d1 + d2 + d3;
    sd[tid] = s;
    __syncthreads();
    for (int off = 1; off < 256; off <<= 1) {
        int v = (tid >= off) ? sd[tid - off] : 0;
        __syncthreads();
        sd[tid] += v;
        __syncthreads();
    }
    int excl = sd[tid] - s;
    if (base < N_NODES) row_start[base] = excl;
    if (base + 1 < N_NODES) row_start[base + 1] = excl + d0;
    if (base + 2 < N_NODES) row_start[base + 2] = excl + d0 + d1;
    if (base + 3 < N_NODES) row_start[base + 3] = excl + d0 + d1 + d2;
    if (tid == 255) bsum[blockIdx.x] = sd[255];
}

__global__ void scan2(int* __restrict__ bsum, int nb) {
    __shared__ int sd[128];
    int tid = threadIdx.x;
    int v = (tid < nb) ? bsum[tid] : 0;
    sd[tid] = v;
    __syncthreads();
    for (int off = 1; off < 128; off <<= 1) {
        int u = (tid >= off) ? sd[tid - off] : 0;
        __syncthreads();
        sd[tid] += u;
        __syncthreads();
    }
    if (tid < nb) bsum[tid] = sd[tid] - v;  // exclusive
}

__global__ void scan3(int* __restrict__ row_start, int* __restrict__ cursor,
                      const int* __restrict__ bsum) {
    int off = bsum[blockIdx.x];
    int base = blockIdx.x * 1024 + threadIdx.x * 4;
#pragma unroll
    for (int j = 0; j < 4; j++) {
        int i = base + j;
        if (i < N_NODES) {
            int v = row_start[i] + off;
            row_start[i] = v;
            cursor[i] = v;
        }
    }
}

// ---------------- CSC fill: bucket src by dst ----------------
__global__ void fill_csr(const int* __restrict__ src, const int* __restrict__ dst,
                         int* __restrict__ cursor, int* __restrict__ csr) {
    int e = blockIdx.x * blockDim.x + threadIdx.x;
    if (e < N_EDGES) {
        int d = dst[e];
        int pos = atomicAdd(&cursor[d], 1);
        csr[pos] = src[e];
    }
}

// ---------------- GEMM1: h1 = x @ W1  [100000x512]@[512x16] ----------------
// thread = one row; x staged through LDS (stride 33 kills bank conflicts);
// W1 accessed with wave-uniform index -> scalar s_load path.
__global__ __launch_bounds__(256) void gemm1(const float* __restrict__ x,
                                             const float* __restrict__ W1,
                                             float* __restrict__ h1) {
    __shared__ float xs[256 * 33];
    int tid = threadIdx.x;
    int row0 = blockIdx.x * 256;
    int row = row0 + tid;
    float acc[16];
#pragma unroll
    for (int c = 0; c < 16; c++) acc[c] = 0.f;

    for (int k0 = 0; k0 < D_IN; k0 += 32) {
        __syncthreads();
#pragma unroll
        for (int l = 0; l < 8; l++) {
            int idx = tid + l * 256;   // 0..2047
            int r = idx >> 3;          // row within block
            int f4 = idx & 7;          // float4 within 32-wide k tile
            int gr = row0 + r;
            float4 v = make_float4(0.f, 0.f, 0.f, 0.f);
            if (gr < N_NODES)
                v = *(const float4*)(x + (size_t)gr * D_IN + k0 + f4 * 4);
            int a = r * 33 + f4 * 4;
            xs[a] = v.x; xs[a + 1] = v.y; xs[a + 2] = v.z; xs[a + 3] = v.w;
        }
        __syncthreads();
#pragma unroll
        for (int kk = 0; kk < 32; kk++) {
            float xv = xs[tid * 33 + kk];
            const float* wr = W1 + (k0 + kk) * 16;  // wave-uniform -> s_load
#pragma unroll
            for (int c = 0; c < 16; c++) acc[c] = fmaf(xv, wr[c], acc[c]);
        }
    }
    if (row < N_NODES) {
        float4* o = (float4*)(h1 + (size_t)row * 16);
        o[0] = make_float4(acc[0], acc[1], acc[2], acc[3]);
        o[1] = make_float4(acc[4], acc[5], acc[6], acc[7]);
        o[2] = make_float4(acc[8], acc[9], acc[10], acc[11]);
        o[3] = make_float4(acc[12], acc[13], acc[14], acc[15]);
    }
}

// ---------------- Agg layer 1 (pull) + bias + ReLU + @W2 fused ----------------
// 16 lanes per node; lane c owns feature c.
__global__ __launch_bounds__(256) void agg1(const float* __restrict__ h1,
                                            const float* __restrict__ dinv,
                                            const int* __restrict__ row_start,
                                            const int* __restrict__ deg,
                                            const int* __restrict__ csr,
                                            const float* __restrict__ b1,
                                            const float* __restrict__ W2,
                                            float* __restrict__ h3) {
    int tid = threadIdx.x;
    int node = blockIdx.x * 16 + (tid >> 4);
    int c = tid & 15;
    if (node >= N_NODES) return;
    float di = dinv[node];
    float acc = h1[(size_t)node * 16 + c] * di * di;  // self-loop
    int start = row_start[node];
    int cnt = deg[node];
    int sN = 0; float vN = 0.f, dN = 0.f;
    if (cnt > 0) {
        sN = csr[start];
        vN = h1[(size_t)sN * 16 + c];
        dN = dinv[sN];
    }
    for (int t = 0; t < cnt; t++) {
        float vC = vN, dC = dN;
        if (t + 1 < cnt) {
            int s = csr[start + t + 1];
            vN = h1[(size_t)s * 16 + c];
            dN = dinv[s];
        }
        acc = fmaf(vC, dC * di, acc);
    }
    float v = acc + b1[c];
    v = v > 0.f ? v : 0.f;
    // out_row = v_row @ W2 (16x16) via in-wave broadcast
    float out = 0.f;
#pragma unroll
    for (int j = 0; j < 16; j++) {
        float vj = __shfl(v, j, 16);
        out = fmaf(vj, W2[j * 16 + c], out);
    }
    h3[(size_t)node * 16 + c] = out;
}

// ---------------- Agg layer 2 (pull) + bias + log_softmax ----------------
__global__ __launch_bounds__(256) void agg2(const float* __restrict__ h3,
                                            const float* __restrict__ dinv,
                                            const int* __restrict__ row_start,
                                            const int* __restrict__ deg,
                                            const int* __restrict__ csr,
                                            const float* __restrict__ b2,
                                            float* __restrict__ out) {
    int tid = threadIdx.x;
    int node = blockIdx.x * 16 + (tid >> 4);
    int c = tid & 15;
    if (node >= N_NODES) return;
    float di = dinv[node];
    float acc = h3[(size_t)node * 16 + c] * di * di;
    int start = row_start[node];
    int cnt = deg[node];
    int sN = 0; float vN = 0.f, dN = 0.f;
    if (cnt > 0) {
        sN = csr[start];
        vN = h3[(size_t)sN * 16 + c];
        dN = dinv[sN];
    }
    for (int t = 0; t < cnt; t++) {
        float vC = vN, dC = dN;
        if (t + 1 < cnt) {
            int s = csr[start + t + 1];
            vN = h3[(size_t)s * 16 + c];
            dN = dinv[s];
        }
        acc = fmaf(vC, dC * di, acc);
    }
    float logit = acc + b2[c];
    // log_softmax over the 16 lanes of this node
    float m = logit;
#pragma unroll
    for (int mask = 1; mask < 16; mask <<= 1)
        m = fmaxf(m, __shfl_xor(m, mask, 16));
    float e = expf(logit - m);
    float ssum = e;
#pragma unroll
    for (int mask = 1; mask < 16; mask <<= 1)
        ssum += __shfl_xor(ssum, mask, 16);
    out[(size_t)node * 16 + c] = (logit - m) - logf(ssum);
}

extern "C" void kernel_launch(void* const* d_in, const int* in_sizes, int n_in,
                              void* d_out, int out_size, void* d_ws, size_t ws_size,
                              hipStream_t stream) {
    const float* x  = (const float*)d_in[0];
    const float* W1 = (const float*)d_in[1];
    const float* b1 = (const float*)d_in[2];
    const float* W2 = (const float*)d_in[3];
    const float* b2 = (const float*)d_in[4];
    const int*   ei = (const int*)d_in[5];
    const int* src = ei;
    const int* dst = ei + N_EDGES;
    float* out = (float*)d_out;

    // workspace layout (elements, all 4B):
    int* deg       = (int*)d_ws;              // 100096
    int* row_start = deg + 100096;            // 100096
    int* cursor    = row_start + 100096;      // 100096
    float* dinv    = (float*)(cursor + 100096); // 100096
    int* bsum      = (int*)(dinv + 100096);   // 128
    int* csr       = bsum + 128;              // 6400000
    float* h1      = (float*)(csr + N_EDGES); // 1600000
    float* h3      = h1 + 1600000;            // 1600000

    hipMemsetAsync(deg, 0, N_NODES * sizeof(int), stream);
    deg_kernel<<<N_EDGES / 256, 256, 0, stream>>>(dst, deg);
    dinv_kernel<<<(N_NODES + 255) / 256, 256, 0, stream>>>(deg, dinv);
    scan1<<<98, 256, 0, stream>>>(deg, row_start, bsum);
    scan2<<<1, 128, 0, stream>>>(bsum, 98);
    scan3<<<98, 256, 0, stream>>>(row_start, cursor, bsum);
    fill_csr<<<N_EDGES / 256, 256, 0, stream>>>(src, dst, cursor, csr);
    gemm1<<<(N_NODES + 255) / 256, 256, 0, stream>>>(x, W1, h1);
    agg1<<<(N_NODES + 15) / 16, 256, 0, stream>>>(h1, dinv, row_start, deg, csr, b1, W2, h3);
    agg2<<<(N_NODES + 15) / 16, 256, 0, stream>>>(h3, dinv, row_start, deg, csr, b2, out);
}